// Round 6
// baseline (1221.792 us; speedup 1.0000x reference)
//
#include <hip/hip_runtime.h>
#include <hip/hip_bf16.h>

using short8 = __attribute__((ext_vector_type(8))) short;
using f32x4  = __attribute__((ext_vector_type(4))) float;

#define DDIM 512
#define NROWS 1024
#define CCLS 100000
#define NCT 782           // c-tiles of 128 (0..781), rows >= CCLS zero-padded
#define GRID_BLOCKS 1536  // 6 per CU, persistent grid-stride

__device__ inline unsigned int f2bf(float f) {
    unsigned int u = __float_as_uint(f);
    u += 0x7FFFu + ((u >> 16) & 1u);   // round-to-nearest-even
    return u >> 16;
}

__device__ inline unsigned int pk2(float x, float y) {
    unsigned int r;
    asm("v_cvt_pk_bf16_f32 %0, %1, %2" : "=v"(r) : "v"(x), "v"(y));
    return r;  // low16 = bf16(x), high16 = bf16(y)
}

// ---------------- kernel 1: normalize x rows -> bf16 ----------------
__global__ __launch_bounds__(256) void norm_x(const float* __restrict__ x,
                                              unsigned short* __restrict__ xn) {
    const int row = blockIdx.x;
    const int tid = threadIdx.x;
    float2 v = *(const float2*)(x + (size_t)row * DDIM + tid * 2);
    float ss = v.x * v.x + v.y * v.y;
#pragma unroll
    for (int m = 1; m < 64; m <<= 1) ss += __shfl_xor(ss, m);
    __shared__ float wsum[4];
    if ((tid & 63) == 0) wsum[tid >> 6] = ss;
    __syncthreads();
    float inv = 1.0f / sqrtf(wsum[0] + wsum[1] + wsum[2] + wsum[3]);
    unsigned int packed = f2bf(v.x * inv) | (f2bf(v.y * inv) << 16);
    ((unsigned int*)xn)[(size_t)row * (DDIM / 2) + tid] = packed;
}

// ---------------- kernel 2: fused W-norm + GEMM + exp-rowsum + target ----------------
// R1 structure (fastest measured; minimal VGPR): 128x128 tile, BK=64, 4 waves
// (2x2), single 16 KB swizzled B buffer, 2 barriers/k-step, A direct from
// L2-resident xn, straight-line load->cvt_pk->ds_write staging (no prefetch
// registers). New in R6:
//  - persistent grid-stride blocks (1536 = 6/CU): one ramp, no dispatch cap,
//    latency hidden by 6 independent block-streams per CU (m114 wave overlap)
//  - XCD-windowed pair order: XCD x owns c-tiles {x, x+8, ...}, mt fast ->
//    the 8 m-blocks of a c-tile run concurrently on one XCD (W L2-shared)
//  - winv computed in-block during staging (no separate norm_w pass)
__global__ __launch_bounds__(256, 6) void arc_gemm(
    const unsigned short* __restrict__ xn,   // [1024][512] bf16
    const float* __restrict__ W,             // [C][512] f32
    const int* __restrict__ labels,          // [1024]
    float* __restrict__ rowsum,              // [1024] (pre-zeroed)
    float* __restrict__ tcos)                // [1024]
{
    __shared__ unsigned short lsB[8192];     // 16 KB, XOR-swizzled
    __shared__ float linv[128];
    __shared__ float lrow[128];
    __shared__ int   llab[128];

    const int tid  = threadIdx.x;
    const int lane = tid & 63;
    const int wid  = tid >> 6;
    const int wr   = wid >> 1, wc = wid & 1;
    const int q    = lane >> 4;
    const int fr   = lane & 15;

    // staging geometry: thread covers rows it*16+srow, float4-chunk sch
    const int srow = tid >> 4;
    const int sch  = tid & 15;
    const int sbase = srow * 128 + ((sch * 8) ^ ((srow & 7) << 4)); // swizzle const

    // persistent-block work list: nominal XCD x = b&7 owns c-tiles {x, x+8, ...}
    const int x = blockIdx.x & 7;
    const int s = blockIdx.x >> 3;           // 0..191 within XCD
    const int nct = (NCT - 1 - x) / 8 + 1;   // 98 (x<6) or 97
    const int npairs = nct * 8;

    for (int p = s; p < npairs; p += GRID_BLOCKS / 8) {
        const int ct = x + 8 * (p >> 3);
        const int mt = p & 7;
        const int c0 = ct * 128;
        const int m0 = mt * 128;

        if (tid < 128) { lrow[tid] = 0.0f; llab[tid] = labels[m0 + tid]; }

        float ss[8];
#pragma unroll
        for (int it = 0; it < 8; ++it) ss[it] = 0.0f;

        f32x4 acc[4][4];
#pragma unroll
        for (int i = 0; i < 4; ++i)
#pragma unroll
            for (int j = 0; j < 4; ++j) acc[i][j] = (f32x4)(0.0f);

        const unsigned short* aBase =
            xn + (size_t)(m0 + wr * 64 + fr) * DDIM + q * 8;

#pragma unroll 1
        for (int k0 = 0; k0 < DDIM; k0 += 64) {
            __syncthreads();
            // stage B chunk: 128 classes x 64 k, f32 -> bf16 (straight-line,
            // minimal live regs; compiler pipelines the 8 iterations)
#pragma unroll
            for (int it = 0; it < 8; ++it) {
                int c = c0 + it * 16 + srow;
                float4 v;
                if (c < CCLS) v = *(const float4*)(W + (size_t)c * DDIM + k0 + sch * 4);
                else          v = make_float4(0.f, 0.f, 0.f, 0.f);
                ss[it] += v.x * v.x + v.y * v.y + v.z * v.z + v.w * v.w;
                *(uint2*)((char*)lsB + it * 2048 + sbase) =
                    make_uint2(pk2(v.x, v.y), pk2(v.z, v.w));
            }
            __syncthreads();

#pragma unroll
            for (int ks = 0; ks < 2; ++ks) {
                short8 af[4], bg[4];
#pragma unroll
                for (int i = 0; i < 4; ++i)
                    af[i] = *(const short8*)(aBase + (size_t)i * 16 * DDIM + k0 + ks * 32);
                const int cb = (ks * 64 + q * 16) ^ ((fr & 7) << 4);
#pragma unroll
                for (int j = 0; j < 4; ++j)
                    bg[j] = *(const short8*)((const char*)lsB
                            + (wc * 64 + j * 16 + fr) * 128 + cb);
#pragma unroll
                for (int i = 0; i < 4; ++i)
#pragma unroll
                    for (int j = 0; j < 4; ++j)
                        acc[i][j] = __builtin_amdgcn_mfma_f32_16x16x32_bf16(
                            af[i], bg[j], acc[i][j], 0, 0, 0);
            }
        }

        // ---- per-class inverse norms (16-lane reduce of staged sumsq) ----
#pragma unroll
        for (int it = 0; it < 8; ++it) {
            float sv = ss[it];
            sv += __shfl_xor(sv, 1);
            sv += __shfl_xor(sv, 2);
            sv += __shfl_xor(sv, 4);
            sv += __shfl_xor(sv, 8);
            if (sch == 0)
                linv[it * 16 + srow] = (sv > 0.0f) ? (1.0f / sqrtf(sv)) : 0.0f;
        }
        __syncthreads();

        // ---- epilogue: cos = acc*winv; exp-sum; target capture ----
        float wv[4]; int colj[4], cok[4];
#pragma unroll
        for (int j = 0; j < 4; ++j) {
            int rc  = wc * 64 + j * 16 + fr;
            colj[j] = c0 + rc;
            cok[j]  = (colj[j] < CCLS) ? 1 : 0;
            wv[j]   = linv[rc];
        }
#pragma unroll
        for (int i = 0; i < 4; ++i) {
#pragma unroll
            for (int v = 0; v < 4; ++v) {
                const int rl  = wr * 64 + i * 16 + q * 4 + v;
                const int lab = llab[rl];
                float sm = 0.0f;
#pragma unroll
                for (int j = 0; j < 4; ++j) {
                    float cv = acc[i][j][v] * wv[j];
                    if (cok[j]) sm += __expf(64.0f * cv);
                    if (colj[j] == lab) tcos[m0 + rl] = cv;
                }
                sm += __shfl_xor(sm, 1);
                sm += __shfl_xor(sm, 2);
                sm += __shfl_xor(sm, 4);
                sm += __shfl_xor(sm, 8);
                if (fr == 0) atomicAdd(&lrow[rl], sm);
            }
        }
        __syncthreads();
        if (tid < 128) atomicAdd(&rowsum[m0 + tid], lrow[tid]);
        __syncthreads();   // protect lrow/llab reset by next pair
    }
}

// ---------------- kernel 3: final loss ----------------
__global__ __launch_bounds__(256) void arc_final(const float* __restrict__ rowsum,
                                                 const float* __restrict__ tcos,
                                                 float* __restrict__ out) {
    const int tid = threadIdx.x;
    const float cosM = 0.87758256189037271612f;  // cos(0.5)
    const float sinM = 0.47942553860420300027f;  // sin(0.5)
    float L = 0.0f;
    for (int n = tid; n < NROWS; n += 256) {
        float tc  = tcos[n];
        float tcl = fminf(fmaxf(tc, -1.0f + 1e-7f), 1.0f - 1e-7f);
        float num = 64.0f * (tcl * cosM - sinM * sqrtf(fmaxf(0.0f, 1.0f - tcl * tcl)));
        float den = __expf(num) + rowsum[n] - __expf(64.0f * tc);
        L += num - logf(den);
    }
    __shared__ float red[256];
    red[tid] = L;
    __syncthreads();
    for (int s = 128; s > 0; s >>= 1) {
        if (tid < s) red[tid] += red[tid + s];
        __syncthreads();
    }
    if (tid == 0) out[0] = -(red[0] / (float)NROWS);
}

// ---------------- launch ----------------
extern "C" void kernel_launch(void* const* d_in, const int* in_sizes, int n_in,
                              void* d_out, int out_size, void* d_ws, size_t ws_size,
                              hipStream_t stream) {
    const float* x      = (const float*)d_in[0];
    const float* W      = (const float*)d_in[1];
    const int*   labels = (const int*)d_in[2];
    float* out = (float*)d_out;
    char*  ws  = (char*)d_ws;

    unsigned short* xn = (unsigned short*)(ws);            // 1,048,576 B
    float* rowsum      = (float*)(ws + 1048576);           // 4,096 B
    float* tcos        = (float*)(ws + 1048576 + 4096);    // 4,096 B

    (void)hipMemsetAsync(rowsum, 0, NROWS * sizeof(float), stream);

    norm_x<<<NROWS, 256, 0, stream>>>(x, xn);

    arc_gemm<<<GRID_BLOCKS, 256, 0, stream>>>(xn, W, labels, rowsum, tcos);

    arc_final<<<1, 256, 0, stream>>>(rowsum, tcos, out);
}

// Round 7
// 454.341 us; speedup vs baseline: 2.6891x; 2.6891x over previous
//
#include <hip/hip_runtime.h>
#include <hip/hip_bf16.h>

using short8 = __attribute__((ext_vector_type(8))) short;
using f32x4  = __attribute__((ext_vector_type(4))) float;

#define DDIM 512
#define NROWS 1024
#define CCLS 100000
#define BN 64
#define NCT 1563          // c-tiles of 64 (0..1562), rows >= CCLS zeroed
#define GRID_BLOCKS 2048  // persistent, XCD-windowed

__device__ inline unsigned int f2bf(float f) {
    unsigned int u = __float_as_uint(f);
    u += 0x7FFFu + ((u >> 16) & 1u);   // round-to-nearest-even
    return u >> 16;
}

__device__ inline unsigned int pk2(float x, float y) {
    unsigned int r;
    asm("v_cvt_pk_bf16_f32 %0, %1, %2" : "=v"(r) : "v"(x), "v"(y));
    return r;  // low16 = bf16(x), high16 = bf16(y)
}

// ---------------- kernel 1: normalize x rows -> bf16 ----------------
__global__ __launch_bounds__(256) void norm_x(const float* __restrict__ x,
                                              unsigned short* __restrict__ xn) {
    const int row = blockIdx.x;
    const int tid = threadIdx.x;
    float2 v = *(const float2*)(x + (size_t)row * DDIM + tid * 2);
    float ss = v.x * v.x + v.y * v.y;
#pragma unroll
    for (int m = 1; m < 64; m <<= 1) ss += __shfl_xor(ss, m);
    __shared__ float wsum[4];
    if ((tid & 63) == 0) wsum[tid >> 6] = ss;
    __syncthreads();
    float inv = 1.0f / sqrtf(wsum[0] + wsum[1] + wsum[2] + wsum[3]);
    unsigned int packed = f2bf(v.x * inv) | (f2bf(v.y * inv) << 16);
    ((unsigned int*)xn)[(size_t)row * (DDIM / 2) + tid] = packed;
}

// ---------------- kernel 2: fused W-norm + GEMM + exp-rowsum + target ----------------
// 128(m) x 64(c) tile, BK=64, 4 waves (2x2; per wave 64x32 -> acc[4][2] = 32
// acc regs). Total regs/wave ~100-110 -> the <=128 bucket -> 16 waves/CU
// (4 blocks/CU), 2x R1's concurrency, NO spill (R6's failure mode).
//  - single 8 KB swizzled B buffer, 2 barriers/k-step (R1's proven loop)
//  - A direct from L2-resident xn
//  - persistent XCD-windowed pairs: XCD x owns c-tiles {x,x+8,...}, mt fast
//    -> concurrent blocks on an XCD share the same W tile (L2-shared)
//  - winv computed in-block during staging
__global__ __launch_bounds__(256, 4) void arc_gemm(
    const unsigned short* __restrict__ xn,   // [1024][512] bf16
    const float* __restrict__ W,             // [C][512] f32
    const int* __restrict__ labels,          // [1024]
    float* __restrict__ rowsum,              // [1024] (pre-zeroed)
    float* __restrict__ tcos)                // [1024]
{
    __shared__ unsigned short lsB[BN * 64];  // 8 KB, XOR-swizzled
    __shared__ float linv[BN];
    __shared__ float lrow[128];
    __shared__ int   llab[128];

    const int tid  = threadIdx.x;
    const int lane = tid & 63;
    const int wid  = tid >> 6;
    const int wr   = wid >> 1, wc = wid & 1;
    const int q    = lane >> 4;
    const int fr   = lane & 15;

    // staging geometry: thread covers rows it*16+srow (it=0..3), chunk sch
    const int srow = tid >> 4;               // 0..15
    const int sch  = tid & 15;
    const int sbase = srow * 128 + ((sch * 8) ^ ((srow & 7) << 4));

    // persistent work list: XCD x owns c-tiles {x, x+8, ...}, mt fast
    const int x = blockIdx.x & 7;
    const int s = blockIdx.x >> 3;           // 0..255 within XCD
    const int nct = (NCT - 1 - x) / 8 + 1;
    const int npairs = nct * 8;

    for (int p = s; p < npairs; p += GRID_BLOCKS / 8) {
        const int ct = x + 8 * (p >> 3);
        const int mt = p & 7;
        const int c0 = ct * BN;
        const int m0 = mt * 128;

        if (tid < 128) { lrow[tid] = 0.0f; llab[tid] = labels[m0 + tid]; }

        float ss[4];
#pragma unroll
        for (int it = 0; it < 4; ++it) ss[it] = 0.0f;

        f32x4 acc[4][2];
#pragma unroll
        for (int i = 0; i < 4; ++i)
#pragma unroll
            for (int j = 0; j < 2; ++j) acc[i][j] = (f32x4)(0.0f);

        const unsigned short* aBase =
            xn + (size_t)(m0 + wr * 64 + fr) * DDIM + q * 8;

#pragma unroll 1
        for (int k0 = 0; k0 < DDIM; k0 += 64) {
            __syncthreads();
            // stage B chunk: 64 classes x 64 k, f32 -> bf16
#pragma unroll
            for (int it = 0; it < 4; ++it) {
                int c = c0 + it * 16 + srow;
                float4 v;
                if (c < CCLS) v = *(const float4*)(W + (size_t)c * DDIM + k0 + sch * 4);
                else          v = make_float4(0.f, 0.f, 0.f, 0.f);
                ss[it] += v.x * v.x + v.y * v.y + v.z * v.z + v.w * v.w;
                *(uint2*)((char*)lsB + it * 2048 + sbase) =
                    make_uint2(pk2(v.x, v.y), pk2(v.z, v.w));
            }
            __syncthreads();

#pragma unroll
            for (int ks = 0; ks < 2; ++ks) {
                short8 af[4], bg[2];
#pragma unroll
                for (int i = 0; i < 4; ++i)
                    af[i] = *(const short8*)(aBase + (size_t)i * 16 * DDIM + k0 + ks * 32);
                const int cb = (ks * 64 + q * 16) ^ ((fr & 7) << 4);
#pragma unroll
                for (int j = 0; j < 2; ++j)
                    bg[j] = *(const short8*)((const char*)lsB
                            + (wc * 32 + j * 16 + fr) * 128 + cb);
#pragma unroll
                for (int i = 0; i < 4; ++i)
#pragma unroll
                    for (int j = 0; j < 2; ++j)
                        acc[i][j] = __builtin_amdgcn_mfma_f32_16x16x32_bf16(
                            af[i], bg[j], acc[i][j], 0, 0, 0);
            }
        }

        // ---- per-class inverse norms (16-lane reduce of staged sumsq) ----
#pragma unroll
        for (int it = 0; it < 4; ++it) {
            float sv = ss[it];
            sv += __shfl_xor(sv, 1);
            sv += __shfl_xor(sv, 2);
            sv += __shfl_xor(sv, 4);
            sv += __shfl_xor(sv, 8);
            if (sch == 0)
                linv[it * 16 + srow] = (sv > 0.0f) ? (1.0f / sqrtf(sv)) : 0.0f;
        }
        __syncthreads();

        // ---- epilogue: cos = acc*winv; exp-sum; target capture ----
#pragma unroll
        for (int i = 0; i < 4; ++i) {
#pragma unroll
            for (int v = 0; v < 4; ++v) {
                const int rl  = wr * 64 + i * 16 + q * 4 + v;
                const int lab = llab[rl];
                float sm = 0.0f;
#pragma unroll
                for (int j = 0; j < 2; ++j) {
                    int rc = wc * 32 + j * 16 + fr;
                    int cj = c0 + rc;
                    float cv = acc[i][j][v] * linv[rc];
                    if (cj < CCLS) sm += __expf(64.0f * cv);
                    if (cj == lab) tcos[m0 + rl] = cv;
                }
                sm += __shfl_xor(sm, 1);
                sm += __shfl_xor(sm, 2);
                sm += __shfl_xor(sm, 4);
                sm += __shfl_xor(sm, 8);
                if (fr == 0) atomicAdd(&lrow[rl], sm);
            }
        }
        __syncthreads();
        if (tid < 128) atomicAdd(&rowsum[m0 + tid], lrow[tid]);
        __syncthreads();   // protect lrow/llab reset by next pair
    }
}

// ---------------- kernel 3: final loss ----------------
__global__ __launch_bounds__(256) void arc_final(const float* __restrict__ rowsum,
                                                 const float* __restrict__ tcos,
                                                 float* __restrict__ out) {
    const int tid = threadIdx.x;
    const float cosM = 0.87758256189037271612f;  // cos(0.5)
    const float sinM = 0.47942553860420300027f;  // sin(0.5)
    float L = 0.0f;
    for (int n = tid; n < NROWS; n += 256) {
        float tc  = tcos[n];
        float tcl = fminf(fmaxf(tc, -1.0f + 1e-7f), 1.0f - 1e-7f);
        float num = 64.0f * (tcl * cosM - sinM * sqrtf(fmaxf(0.0f, 1.0f - tcl * tcl)));
        float den = __expf(num) + rowsum[n] - __expf(64.0f * tc);
        L += num - logf(den);
    }
    __shared__ float red[256];
    red[tid] = L;
    __syncthreads();
    for (int s = 128; s > 0; s >>= 1) {
        if (tid < s) red[tid] += red[tid + s];
        __syncthreads();
    }
    if (tid == 0) out[0] = -(red[0] / (float)NROWS);
}

// ---------------- launch ----------------
extern "C" void kernel_launch(void* const* d_in, const int* in_sizes, int n_in,
                              void* d_out, int out_size, void* d_ws, size_t ws_size,
                              hipStream_t stream) {
    const float* x      = (const float*)d_in[0];
    const float* W      = (const float*)d_in[1];
    const int*   labels = (const int*)d_in[2];
    float* out = (float*)d_out;
    char*  ws  = (char*)d_ws;

    unsigned short* xn = (unsigned short*)(ws);            // 1,048,576 B
    float* rowsum      = (float*)(ws + 1048576);           // 4,096 B
    float* tcos        = (float*)(ws + 1048576 + 4096);    // 4,096 B

    (void)hipMemsetAsync(rowsum, 0, NROWS * sizeof(float), stream);

    norm_x<<<NROWS, 256, 0, stream>>>(x, xn);

    arc_gemm<<<GRID_BLOCKS, 256, 0, stream>>>(xn, W, labels, rowsum, tcos);

    arc_final<<<1, 256, 0, stream>>>(rowsum, tcos, out);
}

// Round 8
// 265.311 us; speedup vs baseline: 4.6051x; 1.7125x over previous
//
#include <hip/hip_runtime.h>
#include <hip/hip_bf16.h>

using short8 = __attribute__((ext_vector_type(8))) short;
using f32x4  = __attribute__((ext_vector_type(4))) float;
using u32x4  = __attribute__((ext_vector_type(4))) unsigned int;

#define DDIM 512
#define NROWS 1024
#define CCLS 100000
#define BN 64
#define NCT 1563          // c-tiles of 64
#define CPAD (NCT * 64)   // 100032 padded classes (winv zero-padded)
#define GRID_BLOCKS 1024  // 4 per CU co-resident, persistent

__device__ inline unsigned int f2bf(float f) {
    unsigned int u = __float_as_uint(f);
    u += 0x7FFFu + ((u >> 16) & 1u);
    return u >> 16;
}

__device__ inline unsigned int pk2(float x, float y) {
    unsigned int r;
    asm("v_cvt_pk_bf16_f32 %0, %1, %2" : "=v"(r) : "v"(x), "v"(y));
    return r;
}

__device__ inline void gload_lds16(const void* g, void* l) {
    __builtin_amdgcn_global_load_lds(
        (const __attribute__((address_space(1))) void*)g,
        (__attribute__((address_space(3))) void*)l, 16, 0, 0);
}

// ---------------- kernel 1: normalize x rows -> bf16 ----------------
__global__ __launch_bounds__(256) void norm_x(const float* __restrict__ x,
                                              unsigned short* __restrict__ xn) {
    const int row = blockIdx.x;
    const int tid = threadIdx.x;
    float2 v = *(const float2*)(x + (size_t)row * DDIM + tid * 2);
    float ss = v.x * v.x + v.y * v.y;
#pragma unroll
    for (int m = 1; m < 64; m <<= 1) ss += __shfl_xor(ss, m);
    __shared__ float wsum[4];
    if ((tid & 63) == 0) wsum[tid >> 6] = ss;
    __syncthreads();
    float inv = 1.0f / sqrtf(wsum[0] + wsum[1] + wsum[2] + wsum[3]);
    unsigned int packed = f2bf(v.x * inv) | (f2bf(v.y * inv) << 16);
    ((unsigned int*)xn)[(size_t)row * (DDIM / 2) + tid] = packed;
}

// ---------------- kernel 2: per-class inverse norm (also warms L3 with W) ----
__global__ __launch_bounds__(256) void norm_w(const float* __restrict__ W,
                                              float* __restrict__ winv) {
    const int row  = blockIdx.x * 4 + (threadIdx.x >> 6);
    const int lane = threadIdx.x & 63;
    if (row < CCLS) {
        const float4* p = (const float4*)(W + (size_t)row * DDIM + lane * 8);
        float4 a = p[0], b = p[1];
        float ss = a.x*a.x + a.y*a.y + a.z*a.z + a.w*a.w
                 + b.x*b.x + b.y*b.y + b.z*b.z + b.w*b.w;
#pragma unroll
        for (int m = 1; m < 64; m <<= 1) ss += __shfl_xor(ss, m);
        if (lane == 0) winv[row] = (ss > 0.0f) ? (1.0f / sqrtf(ss)) : 0.0f;
    } else if (lane == 0) {
        winv[row] = 0.0f;   // padded tail
    }
}

// ---------------- kernel 3: GEMM + exp-rowsum + target (m97-shaped) ----------
// 128(m) x 64(c) tile, BK=64, 4 waves (2x2), acc[4][2]. Per k-step:
//   barrier -> 8x global_load_lds (A bf16 16KB + W f32 16KB, pre-swizzled
//   sources, linear dest) -> barrier(vmcnt drain) -> pure-LDS compute
//   (ds_read_b128 + cvt_pk + 16 MFMA/wave). Staging uses ZERO VALU/VGPRs;
//   compute has ZERO global-latency.
// Persistent XCD-windowed pairs: XCD x owns c-tiles {x,x+8,..}, mt fast ->
// 8 concurrent m-blocks share each W tile in their XCD's L2.
__global__ __launch_bounds__(256, 4) void arc_gemm(
    const unsigned short* __restrict__ xn,   // [1024][512] bf16
    const float* __restrict__ W,             // [C][512] f32
    const float* __restrict__ winv,          // [CPAD]
    const int* __restrict__ labels,          // [1024]
    float* __restrict__ rowsum,              // [1024] (pre-zeroed)
    float* __restrict__ tcos)                // [1024]
{
    __shared__ __align__(16) unsigned short lsA[128 * 64]; // 16 KB
    __shared__ __align__(16) float          lsW[64 * 64];  // 16 KB
    __shared__ float lrow[128];
    __shared__ int   llab[128];

    const int tid  = threadIdx.x;
    const int lane = tid & 63;
    const int wid  = tid >> 6;
    const int wr   = wid >> 1, wc = wid & 1;
    const int q    = lane >> 4;
    const int fr   = lane & 15;

    // DMA source geometry (dest is linear; source column pre-swizzled, rule #21)
    const int arow = tid >> 3;                         // A: +it*32, 8 chunks/row
    const int acol = ((tid & 7) ^ (arow & 7)) * 8;     // u16 units
    const int wrow = tid >> 4;                         // W: +it*16, 16 chunks/row
    const int wcolf = ((tid & 15) ^ (wrow & 7)) * 4;   // float units

    const int x = blockIdx.x & 7;
    const int s = blockIdx.x >> 3;          // 0..127 within XCD window
    const int nct = (NCT - 1 - x) / 8 + 1;
    const int npairs = nct * 8;

    for (int p = s; p < npairs; p += GRID_BLOCKS / 8) {
        const int ct = x + 8 * (p >> 3);
        const int mt = p & 7;
        const int c0 = ct * BN;
        const int m0 = mt * 128;

        if (tid < 128) { lrow[tid] = 0.0f; llab[tid] = labels[m0 + tid]; }

        f32x4 acc[4][2];
#pragma unroll
        for (int i = 0; i < 4; ++i)
#pragma unroll
            for (int j = 0; j < 2; ++j) acc[i][j] = (f32x4)(0.0f);

#pragma unroll 1
        for (int k = 0; k < 8; ++k) {
            const int k0 = k * 64;
            __syncthreads();   // previous compute done; LDS free (also llab/lrow visible)
#pragma unroll
            for (int it = 0; it < 4; ++it)
                gload_lds16(xn + (size_t)(m0 + it * 32 + arow) * DDIM + k0 + acol,
                            (char*)lsA + (it * 256 + wid * 64) * 16);
#pragma unroll
            for (int it = 0; it < 4; ++it) {
                int c = c0 + it * 16 + wrow;
                if (c > CCLS - 1) c = CCLS - 1;   // clamp (masked in epilogue)
                gload_lds16(W + (size_t)c * DDIM + k0 + wcolf,
                            (char*)lsW + (it * 256 + wid * 64) * 16);
            }
            __syncthreads();   // vmcnt(0) drain -> tiles ready

#pragma unroll
            for (int ks = 0; ks < 2; ++ks) {
                short8 af[4], bg[2];
#pragma unroll
                for (int i = 0; i < 4; ++i) {
                    int row = wr * 64 + i * 16 + fr;
                    af[i] = *(const short8*)((const char*)lsA
                            + row * 128 + (((ks * 4 + q) ^ (row & 7)) << 4));
                }
#pragma unroll
                for (int j = 0; j < 2; ++j) {
                    int rc = wc * 32 + j * 16 + fr;
                    int t2 = (ks * 4 + q) * 2;
                    const char* base = (const char*)lsW + rc * 256;
                    float4 v0 = *(const float4*)(base + (((t2    ) ^ (rc & 7)) << 4));
                    float4 v1 = *(const float4*)(base + (((t2 + 1) ^ (rc & 7)) << 4));
                    u32x4 u = { pk2(v0.x, v0.y), pk2(v0.z, v0.w),
                                pk2(v1.x, v1.y), pk2(v1.z, v1.w) };
                    bg[j] = __builtin_bit_cast(short8, u);
                }
#pragma unroll
                for (int i = 0; i < 4; ++i)
#pragma unroll
                    for (int j = 0; j < 2; ++j)
                        acc[i][j] = __builtin_amdgcn_mfma_f32_16x16x32_bf16(
                            af[i], bg[j], acc[i][j], 0, 0, 0);
            }
        }

        // ---- epilogue: cos = acc*winv; exp-sum; target capture ----
        float wv[2]; int cj[2];
#pragma unroll
        for (int j = 0; j < 2; ++j) {
            cj[j] = c0 + wc * 32 + j * 16 + fr;
            wv[j] = winv[cj[j]];
        }
#pragma unroll
        for (int i = 0; i < 4; ++i) {
#pragma unroll
            for (int v = 0; v < 4; ++v) {
                const int rl  = wr * 64 + i * 16 + q * 4 + v;
                const int lab = llab[rl];
                float sm = 0.0f;
#pragma unroll
                for (int j = 0; j < 2; ++j) {
                    float cv = acc[i][j][v] * wv[j];
                    if (cj[j] < CCLS) sm += __expf(64.0f * cv);
                    if (cj[j] == lab) tcos[m0 + rl] = cv;
                }
                sm += __shfl_xor(sm, 1);
                sm += __shfl_xor(sm, 2);
                sm += __shfl_xor(sm, 4);
                sm += __shfl_xor(sm, 8);
                if (fr == 0) atomicAdd(&lrow[rl], sm);
            }
        }
        __syncthreads();
        if (tid < 128) atomicAdd(&rowsum[m0 + tid], lrow[tid]);
        // next pair: same tid rewrites lrow/llab; first k-loop barrier publishes
    }
}

// ---------------- kernel 4: final loss ----------------
__global__ __launch_bounds__(256) void arc_final(const float* __restrict__ rowsum,
                                                 const float* __restrict__ tcos,
                                                 float* __restrict__ out) {
    const int tid = threadIdx.x;
    const float cosM = 0.87758256189037271612f;  // cos(0.5)
    const float sinM = 0.47942553860420300027f;  // sin(0.5)
    float L = 0.0f;
    for (int n = tid; n < NROWS; n += 256) {
        float tc  = tcos[n];
        float tcl = fminf(fmaxf(tc, -1.0f + 1e-7f), 1.0f - 1e-7f);
        float num = 64.0f * (tcl * cosM - sinM * sqrtf(fmaxf(0.0f, 1.0f - tcl * tcl)));
        float den = __expf(num) + rowsum[n] - __expf(64.0f * tc);
        L += num - logf(den);
    }
    __shared__ float red[256];
    red[tid] = L;
    __syncthreads();
    for (int s = 128; s > 0; s >>= 1) {
        if (tid < s) red[tid] += red[tid + s];
        __syncthreads();
    }
    if (tid == 0) out[0] = -(red[0] / (float)NROWS);
}

// ---------------- launch ----------------
extern "C" void kernel_launch(void* const* d_in, const int* in_sizes, int n_in,
                              void* d_out, int out_size, void* d_ws, size_t ws_size,
                              hipStream_t stream) {
    const float* x      = (const float*)d_in[0];
    const float* W      = (const float*)d_in[1];
    const int*   labels = (const int*)d_in[2];
    float* out = (float*)d_out;
    char*  ws  = (char*)d_ws;

    unsigned short* xn = (unsigned short*)(ws);                 // 1,048,576 B
    float* winv        = (float*)(ws + 1048576);                // 400,128 B
    float* rowsum      = (float*)(ws + 1048576 + 400128);       // 4,096 B
    float* tcos        = (float*)(ws + 1048576 + 400128 + 4096);// 4,096 B

    (void)hipMemsetAsync(rowsum, 0, NROWS * sizeof(float), stream);

    norm_x<<<NROWS, 256, 0, stream>>>(x, xn);
    norm_w<<<CPAD / 4, 256, 0, stream>>>(W, winv);

    arc_gemm<<<GRID_BLOCKS, 256, 0, stream>>>(xn, W, winv, labels, rowsum, tcos);

    arc_final<<<1, 256, 0, stream>>>(rowsum, tcos, out);
}